// Round 1
// baseline (671.293 us; speedup 1.0000x reference)
//
#include <hip/hip_runtime.h>
#include <hip/hip_bf16.h>
#include <stdint.h>

#define TAO_F (0.5f/196.0f)

typedef short s16x8 __attribute__((ext_vector_type(8)));
typedef float f32x4 __attribute__((ext_vector_type(4)));
typedef __attribute__((address_space(1))) const unsigned int u32_g;
typedef __attribute__((address_space(3))) unsigned int u32_l;

__device__ __forceinline__ void async_ld16(const void* g, void* l) {
  __builtin_amdgcn_global_load_lds((u32_g*)g, (u32_l*)l, 16, 0, 0);
}

// ---------------- w transpose + bf16: w[r][ci][co] f32 -> wT[r][co][ci] bf16
__global__ void k_prep_w(const float* __restrict__ w, __hip_bfloat16* __restrict__ wT) {
  __shared__ float tile[64][65];
  int bid = blockIdx.x;                 // 9*8*8 = 576
  int r = bid / 64; int rem = bid - r * 64;
  int cib = (rem >> 3) * 64, cob = (rem & 7) * 64;
  int tid = threadIdx.x;
  int col = tid & 63, rw = tid >> 6;
#pragma unroll
  for (int p = 0; p < 16; ++p) {
    int row = p * 4 + rw;               // ci
    tile[row][col] = w[(size_t)(r * 512 + cib + row) * 512 + cob + col];
  }
  __syncthreads();
#pragma unroll
  for (int p = 0; p < 16; ++p) {
    int row = p * 4 + rw;               // co
    wT[(size_t)(r * 512 + cob + row) * 512 + cib + col] = __float2bfloat16(tile[col][row]);
  }
}

// ---------------- per-(b,c) spatial argmax (first-max tie-break), optional raw copy
__global__ void k_argmax(const float* __restrict__ src, int* __restrict__ idx,
                         float* __restrict__ rawcopy) {
  int t = blockIdx.x * 256 + threadIdx.x;     // 65536 threads: b = t>>9, c = t&511
  const float* p = src + (size_t)(t >> 9) * 196 * 512 + (t & 511);
  float best = -1e30f; int bi = 0;
  if (rawcopy) {
    float* rp = rawcopy + (size_t)(t >> 9) * 196 * 512 + (t & 511);
    for (int s = 0; s < 196; ++s) {
      float v = p[(size_t)s * 512];
      rp[(size_t)s * 512] = v;
      if (v > best) { best = v; bi = s; }
    }
  } else {
    for (int s = 0; s < 196; ++s) {
      float v = p[(size_t)s * 512];
      if (v > best) { best = v; bi = s; }
    }
  }
  idx[t] = bi;
}

// ---------------- mask1: x1 = relu(x*tpl), write x1(f32 out), tpl(out), x1 bf16 into halo buf,
// accumulate per-(b,c) mean into act1[c][gt[b]]
__global__ void k_mask1(const float* __restrict__ in, const int* __restrict__ idx1,
                        const int* __restrict__ gt, float* __restrict__ out_x1,
                        float* __restrict__ out_t1, __hip_bfloat16* __restrict__ x1p,
                        float* __restrict__ act1) {
  int t = blockIdx.x * 256 + threadIdx.x;
  int b = t >> 9, c = t & 511;
  int id = idx1[t];
  int pi = id / 14, pj = id - pi * 14;
  const float* ip = in + (size_t)b * 196 * 512 + c;
  float* ox = out_x1 + (size_t)b * 196 * 512 + c;
  float* ot = out_t1 + (size_t)b * 196 * 512 + c;
  __hip_bfloat16* xp = x1p + ((size_t)(b * 16 + 1) * 16 + 1) * 512 + c;
  float sum = 0.f;
  for (int i = 0; i < 14; ++i) {
    int di = (i > pi) ? (i - pi) : (pi - i);
    for (int j = 0; j < 14; ++j) {
      int d = di + ((j > pj) ? (j - pj) : (pj - j));
      float tpl = TAO_F * fmaxf(1.0f - (float)d / 7.0f, -1.0f);
      float x = ip[(size_t)(i * 14 + j) * 512];
      float m = fmaxf(x * tpl, 0.0f);
      ox[(size_t)(i * 14 + j) * 512] = m;
      ot[(size_t)(i * 14 + j) * 512] = tpl;
      xp[(size_t)(i * 16 + j) * 512] = __float2bfloat16(m);
      sum += m;
    }
  }
  atomicAdd(&act1[c * 10 + gt[b]], sum * (1.0f / 196.0f));
}

// ---------------- mask2: x2 = relu(x3*tpl2) -> out, mean -> act2
__global__ void k_mask2(const float* __restrict__ x3, const int* __restrict__ idx2,
                        const int* __restrict__ gt, float* __restrict__ out_x2,
                        float* __restrict__ act2) {
  int t = blockIdx.x * 256 + threadIdx.x;
  int b = t >> 9, c = t & 511;
  int id = idx2[t];
  int pi = id / 14, pj = id - pi * 14;
  const float* ip = x3 + (size_t)b * 196 * 512 + c;
  float* ox = out_x2 + (size_t)b * 196 * 512 + c;
  float sum = 0.f;
  for (int i = 0; i < 14; ++i) {
    int di = (i > pi) ? (i - pi) : (pi - i);
    for (int j = 0; j < 14; ++j) {
      int d = di + ((j > pj) ? (j - pj) : (pj - j));
      float tpl = TAO_F * fmaxf(1.0f - (float)d / 7.0f, -1.0f);
      float x = ip[(size_t)(i * 14 + j) * 512];
      float m = fmaxf(x * tpl, 0.0f);
      ox[(size_t)(i * 14 + j) * 512] = m;
      sum += m;
    }
  }
  atomicAdd(&act2[c * 10 + gt[b]], sum * (1.0f / 196.0f));
}

// ---------------- implicit-GEMM conv: x3 = relu(x1p (*) wT + b), M=25088 N=512 K=4608
// m97 structure: 128x128 tile, BK=64, global_load_lds(16B), 16x16x32 bf16 MFMA, XOR bank swizzle.
__global__ __launch_bounds__(256, 2) void k_gemm(const __hip_bfloat16* __restrict__ x1p,
                                                 const __hip_bfloat16* __restrict__ wT,
                                                 const float* __restrict__ conv_b,
                                                 float* __restrict__ x3) {
  int bid = blockIdx.x;              // 196 Mtiles * 4 Ntiles
  int nt4 = bid & 3; int mt196 = bid >> 2;
  int m0 = mt196 * 128, co0 = nt4 * 128;
  int tid = threadIdx.x;
  int lane = tid & 63;

  __shared__ short As[128 * 64];     // [m][k] bf16 bits, 16B slots XOR-swizzled by row&7
  __shared__ short Bs[128 * 64];     // [n][k]

  int srow = tid >> 3;               // 0..31 (row within pass)
  int sslot = tid & 7;               // 16B slot within 128B row
  int sx = ((sslot ^ (srow & 7)) * 8);   // swizzled element offset in global 64-run

  int baseA[4];
#pragma unroll
  for (int p = 0; p < 4; ++p) {
    int m = m0 + p * 32 + srow;
    int b = m / 196; int s = m - b * 196; int i = s / 14; int j = s - i * 14;
    baseA[p] = ((b * 16 + i + 1) * 16 + (j + 1)) * 512;
  }
  int baseB[4];
#pragma unroll
  for (int p = 0; p < 4; ++p) baseB[p] = (co0 + p * 32 + srow) * 512;

  f32x4 acc[4][4] = {};

  int m_off = (tid >> 7) * 64;        // wave/2
  int n_off = ((tid >> 6) & 1) * 64;  // wave%2
  int q = lane >> 4;
  int l16 = lane & 15;

  for (int r = 0; r < 9; ++r) {
    int offr = ((r / 3) * 16 + (r % 3) - 17) * 512;   // (di*16+dj)*512
    int wbase = r * 512 * 512;
    for (int cb = 0; cb < 8; ++cb) {
      int ko = cb * 64;
      __syncthreads();
#pragma unroll
      for (int p = 0; p < 4; ++p) {
        async_ld16(x1p + (baseA[p] + offr + ko + sx),
                   &As[(p * 32 + srow) * 64 + sslot * 8]);
        async_ld16(wT + (wbase + baseB[p] + ko + sx),
                   &Bs[(p * 32 + srow) * 64 + sslot * 8]);
      }
      __syncthreads();
#pragma unroll
      for (int kk = 0; kk < 2; ++kk) {
        s16x8 af[4], bf[4];
#pragma unroll
        for (int tt = 0; tt < 4; ++tt) {
          int rowa = m_off + tt * 16 + l16;
          int sa = (kk * 4 + q) ^ (rowa & 7);
          af[tt] = *(const s16x8*)&As[rowa * 64 + sa * 8];
          int rowb = n_off + tt * 16 + l16;
          int sb = (kk * 4 + q) ^ (rowb & 7);
          bf[tt] = *(const s16x8*)&Bs[rowb * 64 + sb * 8];
        }
#pragma unroll
        for (int mt = 0; mt < 4; ++mt)
#pragma unroll
          for (int nt = 0; nt < 4; ++nt)
            acc[mt][nt] = __builtin_amdgcn_mfma_f32_16x16x32_bf16(af[mt], bf[nt], acc[mt][nt], 0, 0, 0);
      }
    }
  }
  // epilogue: bias + relu, C/D layout col=lane&15, row=(lane>>4)*4+reg
#pragma unroll
  for (int nt = 0; nt < 4; ++nt) {
    int col = co0 + n_off + nt * 16 + l16;
    float bias = conv_b[col];
#pragma unroll
    for (int mt = 0; mt < 4; ++mt) {
      int mrow = m0 + m_off + mt * 16 + q * 4;
#pragma unroll
      for (int rg = 0; rg < 4; ++rg) {
        float v = acc[mt][nt][rg] + bias;
        x3[(size_t)(mrow + rg) * 512 + col] = fmaxf(v, 0.0f);
      }
    }
  }
}

// ---------------- dense: pooled(2x2 max of x2) @ dense_w + b -> softmax -> probs[b]
__global__ void k_dense(const float* __restrict__ x2, const float* __restrict__ dw,
                        const float* __restrict__ db, float* __restrict__ probs) {
  int b = blockIdx.x, tid = threadIdx.x;
  float a[10] = {0.f,0.f,0.f,0.f,0.f,0.f,0.f,0.f,0.f,0.f};
  for (int d = tid; d < 25088; d += 256) {
    int c = d & 511;
    int sj = d >> 9;                  // ii*7+jj
    int ii = sj / 7, jj = sj - ii * 7;
    const float* xb = x2 + ((size_t)(b * 14 + 2 * ii) * 14 + 2 * jj) * 512 + c;
    float p0 = xb[0], p1 = xb[512], p2 = xb[14 * 512], p3 = xb[14 * 512 + 512];
    float pm = fmaxf(fmaxf(p0, p1), fmaxf(p2, p3));
    const float* wr = dw + (size_t)d * 10;
#pragma unroll
    for (int t2 = 0; t2 < 10; ++t2) a[t2] += pm * wr[t2];
  }
  __shared__ float red[10];
  if (tid < 10) red[tid] = 0.f;
  __syncthreads();
  int lane = tid & 63;
#pragma unroll
  for (int t2 = 0; t2 < 10; ++t2) {
    float v = a[t2];
    for (int off = 32; off > 0; off >>= 1) v += __shfl_down(v, off);
    if (lane == 0) atomicAdd(&red[t2], v);
  }
  __syncthreads();
  if (tid == 0) {
    float l[10]; float m = -1e30f;
#pragma unroll
    for (int t2 = 0; t2 < 10; ++t2) { l[t2] = red[t2] + db[t2]; m = fmaxf(m, l[t2]); }
    float s = 0.f;
#pragma unroll
    for (int t2 = 0; t2 < 10; ++t2) { l[t2] = expf(l[t2] - m); s += l[t2]; }
    float inv = 1.0f / s;
#pragma unroll
    for (int t2 = 0; t2 < 10; ++t2) probs[b * 10 + t2] = l[t2] * inv;
  }
}

// ---------------- stats: cls bincount + fclass argmax per channel (both layers)
__global__ void k_stats(const float* __restrict__ act1, const float* __restrict__ act2,
                        const float* __restrict__ as1, const float* __restrict__ as2,
                        const float* __restrict__ cs1, const float* __restrict__ cs2,
                        const int* __restrict__ gt, int* __restrict__ fc1, int* __restrict__ fc2) {
  __shared__ int scnt[10];
  int tid = threadIdx.x;              // 512
  if (tid < 10) scnt[tid] = 0;
  __syncthreads();
  if (tid < 128) atomicAdd(&scnt[gt[tid]], 1);
  __syncthreads();
  int c = tid;
  float best1 = -1e30f, best2 = -1e30f; int b1 = 0, b2 = 0;
#pragma unroll
  for (int g = 0; g < 10; ++g) {
    float cnt = (float)scnt[g];
    float cn1 = cs1[g] + cnt;
    float cn2 = cs2[g] + cnt;
    float a1 = act1[c * 10 + g] + as1[c * 10 + g];
    float a2 = act2[c * 10 + g] + as2[c * 10 + g];
    float f1 = (cn1 == 0.f) ? 0.f : a1 / cn1;
    float f2 = (cn2 == 0.f) ? 0.f : a2 / cn2;
    if (f1 > best1) { best1 = f1; b1 = g; }
    if (f2 > best2) { best2 = f2; b2 = g; }
  }
  fc1[c] = b1; fc2[c] = b2;
}

// ---------------- losses: loss = match ? relu(tpl) : 0, tpl regenerated from idx
__global__ void k_loss(const int* __restrict__ idx1, const int* __restrict__ idx2,
                       const int* __restrict__ fc1, const int* __restrict__ fc2,
                       const int* __restrict__ gt, float* __restrict__ o1, float* __restrict__ o2) {
  int t = blockIdx.x * 256 + threadIdx.x;
  int b = t >> 9, c = t & 511;
  int g = gt[b];
  bool m1 = (fc1[c] == g), m2 = (fc2[c] == g);
  int i1 = idx1[t], i2 = idx2[t];
  int p1i = i1 / 14, p1j = i1 - p1i * 14;
  int p2i = i2 / 14, p2j = i2 - p2i * 14;
  float* w1 = o1 + (size_t)b * 196 * 512 + c;
  float* w2 = o2 + (size_t)b * 196 * 512 + c;
  for (int i = 0; i < 14; ++i) {
    int d1i = (i > p1i) ? (i - p1i) : (p1i - i);
    int d2i = (i > p2i) ? (i - p2i) : (p2i - i);
    for (int j = 0; j < 14; ++j) {
      int d1 = d1i + ((j > p1j) ? (j - p1j) : (p1j - j));
      int d2 = d2i + ((j > p2j) ? (j - p2j) : (p2j - j));
      float r1 = TAO_F * fmaxf(1.0f - (float)d1 / 7.0f, 0.0f);
      float r2 = TAO_F * fmaxf(1.0f - (float)d2 / 7.0f, 0.0f);
      w1[(size_t)(i * 14 + j) * 512] = m1 ? r1 : 0.0f;
      w2[(size_t)(i * 14 + j) * 512] = m2 ? r2 : 0.0f;
    }
  }
}

extern "C" void kernel_launch(void* const* d_in, const int* in_sizes, int n_in,
                              void* d_out, int out_size, void* d_ws, size_t ws_size,
                              hipStream_t stream) {
  const float* inputs  = (const float*)d_in[0];
  const int*   gt      = (const int*)d_in[1];
  const float* conv_w  = (const float*)d_in[2];
  const float* conv_b  = (const float*)d_in[3];
  const float* dense_w = (const float*)d_in[4];
  const float* dense_b = (const float*)d_in[5];
  const float* as1     = (const float*)d_in[6];
  const float* as2     = (const float*)d_in[7];
  const float* cs1     = (const float*)d_in[8];
  const float* cs2     = (const float*)d_in[9];

  float* out = (float*)d_out;
  const size_t S = 12845056;              // 128*14*14*512
  float* o_probs = out;                   // 1280
  float* o_x1  = out + 1280;
  float* o_x2  = o_x1 + S;
  float* o_l1  = o_x2 + S;
  float* o_l2  = o_l1 + S;
  float* o_raw = o_l2 + S;
  float* o_t1  = o_raw + S;

  uint8_t* w8 = (uint8_t*)d_ws;
  __hip_bfloat16* x1p = (__hip_bfloat16*)w8;                 // 33,554,432 B
  float* x3  = (float*)(w8 + 33554432);                      // 51,380,224 B
  __hip_bfloat16* wT = (__hip_bfloat16*)(w8 + 84934656);     //  4,718,592 B
  int*   idx1 = (int*)(w8 + 89653248);                       //    262,144 B
  int*   idx2 = (int*)(w8 + 89915392);                       //    262,144 B
  float* act1 = (float*)(w8 + 90177536);                     //     20,480 B
  float* act2 = (float*)(w8 + 90198016);                     //     20,480 B
  int*   fc1  = (int*)(w8 + 90218496);                       //      2,048 B
  int*   fc2  = (int*)(w8 + 90220544);                       //      2,048 B

  hipMemsetAsync(x1p, 0, 33554432, stream);          // zero halo (interior overwritten)
  hipMemsetAsync(act1, 0, 40960, stream);            // act1+act2 contiguous

  k_prep_w<<<576, 256, 0, stream>>>(conv_w, wT);
  k_argmax<<<256, 256, 0, stream>>>(inputs, idx1, o_raw);
  k_mask1 <<<256, 256, 0, stream>>>(inputs, idx1, gt, o_x1, o_t1, x1p, act1);
  k_gemm  <<<784, 256, 0, stream>>>(x1p, wT, conv_b, x3);
  k_argmax<<<256, 256, 0, stream>>>(x3, idx2, nullptr);
  k_mask2 <<<256, 256, 0, stream>>>(x3, idx2, gt, o_x2, act2);
  k_dense <<<128, 256, 0, stream>>>(o_x2, dense_w, dense_b, o_probs);
  k_stats <<<1, 512, 0, stream>>>(act1, act2, as1, as2, cs1, cs2, gt, fc1, fc2);
  k_loss  <<<256, 256, 0, stream>>>(idx1, idx2, fc1, fc2, gt, o_l1, o_l2);
}

// Round 2
// 623.925 us; speedup vs baseline: 1.0759x; 1.0759x over previous
//
#include <hip/hip_runtime.h>
#include <hip/hip_bf16.h>
#include <stdint.h>

#define TAO_F (0.5f/196.0f)

typedef short s16x8 __attribute__((ext_vector_type(8)));
typedef float f32x4 __attribute__((ext_vector_type(4)));
typedef __attribute__((address_space(1))) const unsigned int u32_g;
typedef __attribute__((address_space(3))) unsigned int u32_l;

__device__ __forceinline__ void async_ld16(const void* g, void* l) {
  __builtin_amdgcn_global_load_lds((u32_g*)g, (u32_l*)l, 16, 0, 0);
}

// ---------------- w transpose + bf16: w[r][ci][co] f32 -> wT[r][co][ci] bf16
__global__ void k_prep_w(const float* __restrict__ w, __hip_bfloat16* __restrict__ wT) {
  __shared__ float tile[64][65];
  int bid = blockIdx.x;                 // 9*8*8 = 576
  int r = bid / 64; int rem = bid - r * 64;
  int cib = (rem >> 3) * 64, cob = (rem & 7) * 64;
  int tid = threadIdx.x;
  int col = tid & 63, rw = tid >> 6;
#pragma unroll
  for (int p = 0; p < 16; ++p) {
    int row = p * 4 + rw;               // ci
    tile[row][col] = w[(size_t)(r * 512 + cib + row) * 512 + cob + col];
  }
  __syncthreads();
#pragma unroll
  for (int p = 0; p < 16; ++p) {
    int row = p * 4 + rw;               // co
    wT[(size_t)(r * 512 + cob + row) * 512 + cib + col] = __float2bfloat16(tile[col][row]);
  }
}

// ---------------- fused layer-1: argmax + raw copy + mask + bf16 pack + act1 accum
__global__ void k_fuse1(const float* __restrict__ in, const int* __restrict__ gt,
                        float* __restrict__ o_raw, float* __restrict__ o_x1,
                        float* __restrict__ o_t1, __hip_bfloat16* __restrict__ x1p,
                        float* __restrict__ act1, int* __restrict__ idx1) {
  int t = blockIdx.x * 256 + threadIdx.x;   // b = t>>9, c = t&511
  int b = t >> 9, c = t & 511;
  const float* ip = in + (size_t)b * 196 * 512 + c;
  float* rp = o_raw + (size_t)b * 196 * 512 + c;
  // pass 1: argmax (first-max tie-break) + raw copy
  float best = -1e30f; int bi = 0;
  for (int s = 0; s < 196; ++s) {
    float v = ip[(size_t)s * 512];
    rp[(size_t)s * 512] = v;
    if (v > best) { best = v; bi = s; }
  }
  idx1[t] = bi;
  int pi = bi / 14, pj = bi - pi * 14;
  // pass 2: mask (reads hit L2/LLC)
  float* ox = o_x1 + (size_t)b * 196 * 512 + c;
  float* ot = o_t1 + (size_t)b * 196 * 512 + c;
  __hip_bfloat16* xp = x1p + ((size_t)(b * 16 + 1) * 16 + 1) * 512 + c;
  float sum = 0.f;
  for (int i = 0; i < 14; ++i) {
    int di = (i > pi) ? (i - pi) : (pi - i);
    for (int j = 0; j < 14; ++j) {
      int d = di + ((j > pj) ? (j - pj) : (pj - j));
      float tpl = TAO_F * fmaxf(1.0f - (float)d / 7.0f, -1.0f);
      float x = ip[(size_t)(i * 14 + j) * 512];
      float m = fmaxf(x * tpl, 0.0f);
      ox[(size_t)(i * 14 + j) * 512] = m;
      ot[(size_t)(i * 14 + j) * 512] = tpl;
      xp[(size_t)(i * 16 + j) * 512] = __float2bfloat16(m);
      sum += m;
    }
  }
  atomicAdd(&act1[c * 10 + gt[b]], sum * (1.0f / 196.0f));
}

// ---------------- implicit-GEMM conv: x3 = relu(x1p (*) wT + b), M=25088 N=512 K=4608
// m97 structure: 128x128 tile, BK=64, global_load_lds(16B), 16x16x32 bf16 MFMA, XOR bank swizzle.
// launch_bounds(256,3): 3 blocks/CU -> 768 resident of 784 grid (tail=16), m97's VGPR regime.
__global__ __launch_bounds__(256, 3) void k_gemm(const __hip_bfloat16* __restrict__ x1p,
                                                 const __hip_bfloat16* __restrict__ wT,
                                                 const float* __restrict__ conv_b,
                                                 float* __restrict__ x3) {
  int bid = blockIdx.x;              // 196 Mtiles * 4 Ntiles; bid&3=Ntile keeps B L2-local per XCD
  int nt4 = bid & 3; int mt196 = bid >> 2;
  int m0 = mt196 * 128, co0 = nt4 * 128;
  int tid = threadIdx.x;
  int lane = tid & 63;

  __shared__ short As[128 * 64];     // [m][k] bf16 bits, 16B slots XOR-swizzled by row&7
  __shared__ short Bs[128 * 64];     // [n][k]

  int srow = tid >> 3;               // 0..31 (row within pass)
  int sslot = tid & 7;               // 16B slot within 128B row
  int sx = ((sslot ^ (srow & 7)) * 8);   // swizzled element offset in global 64-run

  int baseA[4];
#pragma unroll
  for (int p = 0; p < 4; ++p) {
    int m = m0 + p * 32 + srow;
    int b = m / 196; int s = m - b * 196; int i = s / 14; int j = s - i * 14;
    baseA[p] = ((b * 16 + i + 1) * 16 + (j + 1)) * 512;
  }
  int baseB[4];
#pragma unroll
  for (int p = 0; p < 4; ++p) baseB[p] = (co0 + p * 32 + srow) * 512;

  f32x4 acc[4][4] = {};

  int m_off = (tid >> 7) * 64;        // wave/2
  int n_off = ((tid >> 6) & 1) * 64;  // wave%2
  int q = lane >> 4;
  int l16 = lane & 15;

  for (int r = 0; r < 9; ++r) {
    int offr = ((r / 3) * 16 + (r % 3) - 17) * 512;   // (di*16+dj)*512
    int wbase = r * 512 * 512;
    for (int cb = 0; cb < 8; ++cb) {
      int ko = cb * 64;
      __syncthreads();
#pragma unroll
      for (int p = 0; p < 4; ++p) {
        async_ld16(x1p + (baseA[p] + offr + ko + sx),
                   &As[(p * 32 + srow) * 64 + sslot * 8]);
        async_ld16(wT + (wbase + baseB[p] + ko + sx),
                   &Bs[(p * 32 + srow) * 64 + sslot * 8]);
      }
      __syncthreads();
#pragma unroll
      for (int kk = 0; kk < 2; ++kk) {
        s16x8 af[4], bf[4];
#pragma unroll
        for (int tt = 0; tt < 4; ++tt) {
          int rowa = m_off + tt * 16 + l16;
          int sa = (kk * 4 + q) ^ (rowa & 7);
          af[tt] = *(const s16x8*)&As[rowa * 64 + sa * 8];
          int rowb = n_off + tt * 16 + l16;
          int sb = (kk * 4 + q) ^ (rowb & 7);
          bf[tt] = *(const s16x8*)&Bs[rowb * 64 + sb * 8];
        }
#pragma unroll
        for (int mt = 0; mt < 4; ++mt)
#pragma unroll
          for (int nt = 0; nt < 4; ++nt)
            acc[mt][nt] = __builtin_amdgcn_mfma_f32_16x16x32_bf16(af[mt], bf[nt], acc[mt][nt], 0, 0, 0);
      }
    }
  }
  // epilogue: bias + relu, C/D layout col=lane&15, row=(lane>>4)*4+reg
#pragma unroll
  for (int nt = 0; nt < 4; ++nt) {
    int col = co0 + n_off + nt * 16 + l16;
    float bias = conv_b[col];
#pragma unroll
    for (int mt = 0; mt < 4; ++mt) {
      int mrow = m0 + m_off + mt * 16 + q * 4;
#pragma unroll
      for (int rg = 0; rg < 4; ++rg) {
        float v = acc[mt][nt][rg] + bias;
        x3[(size_t)(mrow + rg) * 512 + col] = fmaxf(v, 0.0f);
      }
    }
  }
}

// ---------------- fused layer-2: argmax + mask + act2 accum + pooled dense partial
// block = 256 threads = 256 channels of one batch (b = blockIdx>>1) -> per-block logit reduce
__global__ void k_fuse2(const float* __restrict__ x3, const int* __restrict__ gt,
                        const float* __restrict__ dw, float* __restrict__ o_x2,
                        float* __restrict__ act2, float* __restrict__ logits,
                        int* __restrict__ idx2) {
  int t = blockIdx.x * 256 + threadIdx.x;
  int b = t >> 9, c = t & 511;
  const float* ip = x3 + (size_t)b * 196 * 512 + c;
  float best = -1e30f; int bi = 0;
  for (int s = 0; s < 196; ++s) {
    float v = ip[(size_t)s * 512];
    if (v > best) { best = v; bi = s; }
  }
  idx2[t] = bi;
  int pi = bi / 14, pj = bi - pi * 14;
  float* ox = o_x2 + (size_t)b * 196 * 512 + c;
  float sum = 0.f;
  float a[10] = {0.f,0.f,0.f,0.f,0.f,0.f,0.f,0.f,0.f,0.f};
  for (int ii = 0; ii < 7; ++ii) {
    float rv[2][14];
#pragma unroll
    for (int r2 = 0; r2 < 2; ++r2) {
      int i = 2 * ii + r2;
      int di = (i > pi) ? (i - pi) : (pi - i);
#pragma unroll
      for (int j = 0; j < 14; ++j) {
        int d = di + ((j > pj) ? (j - pj) : (pj - j));
        float tpl = TAO_F * fmaxf(1.0f - (float)d / 7.0f, -1.0f);
        float x = ip[(size_t)(i * 14 + j) * 512];
        float m = fmaxf(x * tpl, 0.0f);
        ox[(size_t)(i * 14 + j) * 512] = m;
        sum += m;
        rv[r2][j] = m;
      }
    }
#pragma unroll
    for (int jj = 0; jj < 7; ++jj) {
      float pm = fmaxf(fmaxf(rv[0][2 * jj], rv[0][2 * jj + 1]),
                       fmaxf(rv[1][2 * jj], rv[1][2 * jj + 1]));
      const float* wr = dw + ((size_t)((ii * 7 + jj) * 512 + c)) * 10;
#pragma unroll
      for (int t2 = 0; t2 < 10; ++t2) a[t2] += pm * wr[t2];
    }
  }
  atomicAdd(&act2[c * 10 + gt[b]], sum * (1.0f / 196.0f));
  // per-block logit reduction (one b per block)
  __shared__ float red[10];
  if (threadIdx.x < 10) red[threadIdx.x] = 0.f;
  __syncthreads();
  int lane = threadIdx.x & 63;
#pragma unroll
  for (int t2 = 0; t2 < 10; ++t2) {
    float v = a[t2];
    for (int off = 32; off > 0; off >>= 1) v += __shfl_down(v, off);
    if (lane == 0) atomicAdd(&red[t2], v);
  }
  __syncthreads();
  if (threadIdx.x < 10) atomicAdd(&logits[b * 10 + threadIdx.x], red[threadIdx.x]);
}

// ---------------- stats: cls bincount + fclass argmax per channel + softmax(probs)
__global__ void k_stats(const float* __restrict__ act1, const float* __restrict__ act2,
                        const float* __restrict__ as1, const float* __restrict__ as2,
                        const float* __restrict__ cs1, const float* __restrict__ cs2,
                        const int* __restrict__ gt, const float* __restrict__ logits,
                        const float* __restrict__ db, int* __restrict__ fc1,
                        int* __restrict__ fc2, float* __restrict__ o_probs) {
  __shared__ int scnt[10];
  int tid = threadIdx.x;              // 512
  if (tid < 10) scnt[tid] = 0;
  __syncthreads();
  if (tid < 128) atomicAdd(&scnt[gt[tid]], 1);
  __syncthreads();
  int c = tid;
  float best1 = -1e30f, best2 = -1e30f; int b1 = 0, b2 = 0;
#pragma unroll
  for (int g = 0; g < 10; ++g) {
    float cnt = (float)scnt[g];
    float cn1 = cs1[g] + cnt;
    float cn2 = cs2[g] + cnt;
    float a1 = act1[c * 10 + g] + as1[c * 10 + g];
    float a2 = act2[c * 10 + g] + as2[c * 10 + g];
    float f1 = (cn1 == 0.f) ? 0.f : a1 / cn1;
    float f2 = (cn2 == 0.f) ? 0.f : a2 / cn2;
    if (f1 > best1) { best1 = f1; b1 = g; }
    if (f2 > best2) { best2 = f2; b2 = g; }
  }
  fc1[c] = b1; fc2[c] = b2;
  // softmax (128 batches)
  if (tid < 128) {
    float l[10]; float m = -1e30f;
#pragma unroll
    for (int t2 = 0; t2 < 10; ++t2) { l[t2] = logits[tid * 10 + t2] + db[t2]; m = fmaxf(m, l[t2]); }
    float s = 0.f;
#pragma unroll
    for (int t2 = 0; t2 < 10; ++t2) { l[t2] = expf(l[t2] - m); s += l[t2]; }
    float inv = 1.0f / s;
#pragma unroll
    for (int t2 = 0; t2 < 10; ++t2) o_probs[tid * 10 + t2] = l[t2] * inv;
  }
}

// ---------------- losses: loss = match ? relu(tpl) : 0, tpl regenerated from idx
__global__ void k_loss(const int* __restrict__ idx1, const int* __restrict__ idx2,
                       const int* __restrict__ fc1, const int* __restrict__ fc2,
                       const int* __restrict__ gt, float* __restrict__ o1, float* __restrict__ o2) {
  int t = blockIdx.x * 256 + threadIdx.x;
  int b = t >> 9, c = t & 511;
  int g = gt[b];
  bool m1 = (fc1[c] == g), m2 = (fc2[c] == g);
  int i1 = idx1[t], i2 = idx2[t];
  int p1i = i1 / 14, p1j = i1 - p1i * 14;
  int p2i = i2 / 14, p2j = i2 - p2i * 14;
  float* w1 = o1 + (size_t)b * 196 * 512 + c;
  float* w2 = o2 + (size_t)b * 196 * 512 + c;
  for (int i = 0; i < 14; ++i) {
    int d1i = (i > p1i) ? (i - p1i) : (p1i - i);
    int d2i = (i > p2i) ? (i - p2i) : (p2i - i);
    for (int j = 0; j < 14; ++j) {
      int d1 = d1i + ((j > p1j) ? (j - p1j) : (p1j - j));
      int d2 = d2i + ((j > p2j) ? (j - p2j) : (p2j - j));
      float r1 = TAO_F * fmaxf(1.0f - (float)d1 / 7.0f, 0.0f);
      float r2 = TAO_F * fmaxf(1.0f - (float)d2 / 7.0f, 0.0f);
      w1[(size_t)(i * 14 + j) * 512] = m1 ? r1 : 0.0f;
      w2[(size_t)(i * 14 + j) * 512] = m2 ? r2 : 0.0f;
    }
  }
}

extern "C" void kernel_launch(void* const* d_in, const int* in_sizes, int n_in,
                              void* d_out, int out_size, void* d_ws, size_t ws_size,
                              hipStream_t stream) {
  const float* inputs  = (const float*)d_in[0];
  const int*   gt      = (const int*)d_in[1];
  const float* conv_w  = (const float*)d_in[2];
  const float* conv_b  = (const float*)d_in[3];
  const float* dense_w = (const float*)d_in[4];
  const float* dense_b = (const float*)d_in[5];
  const float* as1     = (const float*)d_in[6];
  const float* as2     = (const float*)d_in[7];
  const float* cs1     = (const float*)d_in[8];
  const float* cs2     = (const float*)d_in[9];

  float* out = (float*)d_out;
  const size_t S = 12845056;              // 128*14*14*512
  float* o_probs = out;                   // 1280
  float* o_x1  = out + 1280;
  float* o_x2  = o_x1 + S;
  float* o_l1  = o_x2 + S;
  float* o_l2  = o_l1 + S;
  float* o_raw = o_l2 + S;
  float* o_t1  = o_raw + S;

  uint8_t* w8 = (uint8_t*)d_ws;
  __hip_bfloat16* x1p = (__hip_bfloat16*)w8;                 // 33,554,432 B
  float* x3  = (float*)(w8 + 33554432);                      // 51,380,224 B
  __hip_bfloat16* wT = (__hip_bfloat16*)(w8 + 84934656);     //  4,718,592 B
  int*   idx1 = (int*)(w8 + 89653248);                       //    262,144 B
  int*   idx2 = (int*)(w8 + 89915392);                       //    262,144 B
  float* act1 = (float*)(w8 + 90177536);                     //     20,480 B
  float* act2 = (float*)(w8 + 90198016);                     //     20,480 B
  float* logits = (float*)(w8 + 90218496);                   //      5,120 B
  int*   fc1  = (int*)(w8 + 90223616);                       //      2,048 B
  int*   fc2  = (int*)(w8 + 90225664);                       //      2,048 B

  hipMemsetAsync(x1p, 0, 33554432, stream);          // zero halo (interior overwritten)
  hipMemsetAsync(act1, 0, 46080, stream);            // act1+act2+logits contiguous

  k_prep_w<<<576, 256, 0, stream>>>(conv_w, wT);
  k_fuse1 <<<256, 256, 0, stream>>>(inputs, gt, o_raw, o_x1, o_t1, x1p, act1, idx1);
  k_gemm  <<<784, 256, 0, stream>>>(x1p, wT, conv_b, x3);
  k_fuse2 <<<256, 256, 0, stream>>>(x3, gt, dense_w, o_x2, act2, logits, idx2);
  k_stats <<<1, 512, 0, stream>>>(act1, act2, as1, as2, cs1, cs2, gt, logits, dense_b,
                                  fc1, fc2, o_probs);
  k_loss  <<<256, 256, 0, stream>>>(idx1, idx2, fc1, fc2, gt, o_l1, o_l2);
}

// Round 3
// 594.507 us; speedup vs baseline: 1.1292x; 1.0495x over previous
//
#include <hip/hip_runtime.h>
#include <hip/hip_bf16.h>
#include <stdint.h>

#define TAO_F (0.5f/196.0f)

typedef short s16x8 __attribute__((ext_vector_type(8)));
typedef float f32x4 __attribute__((ext_vector_type(4)));
typedef __attribute__((address_space(1))) const unsigned int u32_g;
typedef __attribute__((address_space(3))) unsigned int u32_l;

__device__ __forceinline__ void async_ld16(const void* g, void* l) {
  __builtin_amdgcn_global_load_lds((u32_g*)g, (u32_l*)l, 16, 0, 0);
}

// ================= fused layer-1 body: argmax + raw copy + mask + bf16 pack + act1
// block = (b, cg): 32 channels; 256 thr = 8 float4-groups x 32 spatial partitions
__device__ __forceinline__ void fuse1_body(
    int bid, const float* __restrict__ in, const int* __restrict__ gt,
    float* __restrict__ o_raw, float* __restrict__ o_x1, float* __restrict__ o_t1,
    __hip_bfloat16* __restrict__ x1p, float* __restrict__ act1,
    int* __restrict__ idx1, uint8_t* smem) {
  int b = bid >> 4, cg = bid & 15;
  int t = threadIdx.x;
  int c4 = t & 7, sp = t >> 3;
  int c0 = cg * 32 + c4 * 4;
  int cq = c0 >> 2;
  float (*rv)[8][4] = (float(*)[8][4])smem;            // 4096 B
  int   (*ri)[8][4] = (int(*)[8][4])(smem + 4096);     // 4096 B

  const float4* ip = (const float4*)in + (size_t)b * 196 * 128;
  float4* rp = (float4*)o_raw + (size_t)b * 196 * 128;

  // phase A: argmax (first-max) + raw copy, float4
  float bv[4] = {-1e30f, -1e30f, -1e30f, -1e30f};
  int bix[4] = {0, 0, 0, 0};
  for (int s = sp; s < 196; s += 32) {
    float4 v = ip[s * 128 + cq];
    rp[s * 128 + cq] = v;
    float vv[4] = {v.x, v.y, v.z, v.w};
#pragma unroll
    for (int k = 0; k < 4; ++k)
      if (vv[k] > bv[k]) { bv[k] = vv[k]; bix[k] = s; }
  }
#pragma unroll
  for (int k = 0; k < 4; ++k) { rv[sp][c4][k] = bv[k]; ri[sp][c4][k] = bix[k]; }
  __syncthreads();
  for (int st = 16; st >= 1; st >>= 1) {
    if (sp < st) {
#pragma unroll
      for (int k = 0; k < 4; ++k) {
        float v1 = rv[sp][c4][k], v2 = rv[sp + st][c4][k];
        int i1 = ri[sp][c4][k], i2 = ri[sp + st][c4][k];
        if (v2 > v1 || (v2 == v1 && i2 < i1)) { rv[sp][c4][k] = v2; ri[sp][c4][k] = i2; }
      }
    }
    __syncthreads();
  }
  int pi[4], pj[4];
#pragma unroll
  for (int k = 0; k < 4; ++k) {
    int id = ri[0][c4][k];
    pi[k] = id / 14; pj[k] = id - pi[k] * 14;
  }
  if (sp == 0)
    *(int4*)&idx1[b * 512 + c0] = make_int4(ri[0][c4][0], ri[0][c4][1], ri[0][c4][2], ri[0][c4][3]);
  __syncthreads();   // before reusing rv for sums

  // phase B: mask, write x1/t1/x1p(bf16), accumulate sums (input re-read hits L2/LLC)
  float4* xo = (float4*)o_x1 + (size_t)b * 196 * 128;
  float4* to = (float4*)o_t1 + (size_t)b * 196 * 128;
  float sm[4] = {0.f, 0.f, 0.f, 0.f};
  for (int s = sp; s < 196; s += 32) {
    int i = s / 14, j = s - i * 14;
    float4 x = ip[s * 128 + cq];
    float xx[4] = {x.x, x.y, x.z, x.w};
    float tp[4], mm[4];
#pragma unroll
    for (int k = 0; k < 4; ++k) {
      int di = i - pi[k]; di = di < 0 ? -di : di;
      int dj = j - pj[k]; dj = dj < 0 ? -dj : dj;
      tp[k] = TAO_F * fmaxf(1.0f - (float)(di + dj) * (1.0f / 7.0f), -1.0f);
      mm[k] = fmaxf(xx[k] * tp[k], 0.0f);
      sm[k] += mm[k];
    }
    xo[s * 128 + cq] = make_float4(mm[0], mm[1], mm[2], mm[3]);
    to[s * 128 + cq] = make_float4(tp[0], tp[1], tp[2], tp[3]);
    union { ushort4 u4; __hip_bfloat16 h[4]; } cv;
#pragma unroll
    for (int k = 0; k < 4; ++k) cv.h[k] = __float2bfloat16(mm[k]);
    *(ushort4*)&x1p[((size_t)(b * 16 + i + 1) * 16 + (j + 1)) * 512 + c0] = cv.u4;
  }
#pragma unroll
  for (int k = 0; k < 4; ++k) rv[sp][c4][k] = sm[k];
  __syncthreads();
  for (int st = 16; st >= 1; st >>= 1) {
    if (sp < st) {
#pragma unroll
      for (int k = 0; k < 4; ++k) rv[sp][c4][k] += rv[sp + st][c4][k];
    }
    __syncthreads();
  }
  if (sp == 0) {
    int g = gt[b];
#pragma unroll
    for (int k = 0; k < 4; ++k)
      atomicAdd(&act1[(c0 + k) * 10 + g], rv[0][c4][k] * (1.0f / 196.0f));
  }
}

// ================= k_pre: blocks <576 transpose conv_w -> wT bf16; rest = fuse1
__global__ __launch_bounds__(256) void k_pre(
    const float* __restrict__ w, __hip_bfloat16* __restrict__ wT,
    const float* __restrict__ in, const int* __restrict__ gt,
    float* __restrict__ o_raw, float* __restrict__ o_x1, float* __restrict__ o_t1,
    __hip_bfloat16* __restrict__ x1p, float* __restrict__ act1, int* __restrict__ idx1) {
  __shared__ uint8_t smem[16640];
  if (blockIdx.x < 576) {
    float (*tile)[65] = (float(*)[65])smem;
    int bid = blockIdx.x;
    int r = bid / 64; int rem = bid - r * 64;
    int cib = (rem >> 3) * 64, cob = (rem & 7) * 64;
    int tid = threadIdx.x;
    int col = tid & 63, rw = tid >> 6;
#pragma unroll
    for (int p = 0; p < 16; ++p) {
      int row = p * 4 + rw;               // ci
      tile[row][col] = w[(size_t)(r * 512 + cib + row) * 512 + cob + col];
    }
    __syncthreads();
#pragma unroll
    for (int p = 0; p < 16; ++p) {
      int row = p * 4 + rw;               // co
      wT[(size_t)(r * 512 + cob + row) * 512 + cib + col] = __float2bfloat16(tile[col][row]);
    }
  } else {
    fuse1_body(blockIdx.x - 576, in, gt, o_raw, o_x1, o_t1, x1p, act1, idx1, smem);
  }
}

// ================= implicit-GEMM conv: x3 = relu(x1p (*) wT + b), unchanged m97 structure
__global__ __launch_bounds__(256, 3) void k_gemm(const __hip_bfloat16* __restrict__ x1p,
                                                 const __hip_bfloat16* __restrict__ wT,
                                                 const float* __restrict__ conv_b,
                                                 float* __restrict__ x3) {
  int bid = blockIdx.x;              // 196 Mtiles * 4 Ntiles
  int nt4 = bid & 3; int mt196 = bid >> 2;
  int m0 = mt196 * 128, co0 = nt4 * 128;
  int tid = threadIdx.x;
  int lane = tid & 63;

  __shared__ short As[128 * 64];
  __shared__ short Bs[128 * 64];

  int srow = tid >> 3;
  int sslot = tid & 7;
  int sx = ((sslot ^ (srow & 7)) * 8);

  int baseA[4];
#pragma unroll
  for (int p = 0; p < 4; ++p) {
    int m = m0 + p * 32 + srow;
    int b = m / 196; int s = m - b * 196; int i = s / 14; int j = s - i * 14;
    baseA[p] = ((b * 16 + i + 1) * 16 + (j + 1)) * 512;
  }
  int baseB[4];
#pragma unroll
  for (int p = 0; p < 4; ++p) baseB[p] = (co0 + p * 32 + srow) * 512;

  f32x4 acc[4][4] = {};

  int m_off = (tid >> 7) * 64;
  int n_off = ((tid >> 6) & 1) * 64;
  int q = lane >> 4;
  int l16 = lane & 15;

  for (int r = 0; r < 9; ++r) {
    int offr = ((r / 3) * 16 + (r % 3) - 17) * 512;
    int wbase = r * 512 * 512;
    for (int cb = 0; cb < 8; ++cb) {
      int ko = cb * 64;
      __syncthreads();
#pragma unroll
      for (int p = 0; p < 4; ++p) {
        async_ld16(x1p + (baseA[p] + offr + ko + sx),
                   &As[(p * 32 + srow) * 64 + sslot * 8]);
        async_ld16(wT + (wbase + baseB[p] + ko + sx),
                   &Bs[(p * 32 + srow) * 64 + sslot * 8]);
      }
      __syncthreads();
#pragma unroll
      for (int kk = 0; kk < 2; ++kk) {
        s16x8 af[4], bf[4];
#pragma unroll
        for (int tt = 0; tt < 4; ++tt) {
          int rowa = m_off + tt * 16 + l16;
          int sa = (kk * 4 + q) ^ (rowa & 7);
          af[tt] = *(const s16x8*)&As[rowa * 64 + sa * 8];
          int rowb = n_off + tt * 16 + l16;
          int sb = (kk * 4 + q) ^ (rowb & 7);
          bf[tt] = *(const s16x8*)&Bs[rowb * 64 + sb * 8];
        }
#pragma unroll
        for (int mt = 0; mt < 4; ++mt)
#pragma unroll
          for (int nt = 0; nt < 4; ++nt)
            acc[mt][nt] = __builtin_amdgcn_mfma_f32_16x16x32_bf16(af[mt], bf[nt], acc[mt][nt], 0, 0, 0);
      }
    }
  }
#pragma unroll
  for (int nt = 0; nt < 4; ++nt) {
    int col = co0 + n_off + nt * 16 + l16;
    float bias = conv_b[col];
#pragma unroll
    for (int mt = 0; mt < 4; ++mt) {
      int mrow = m0 + m_off + mt * 16 + q * 4;
#pragma unroll
      for (int rg = 0; rg < 4; ++rg) {
        float v = acc[mt][nt][rg] + bias;
        x3[(size_t)(mrow + rg) * 512 + col] = fmaxf(v, 0.0f);
      }
    }
  }
}

// ================= fused layer-2: argmax + mask + act2 + pool + dense partials
// block = (b, cg): 32 channels; x3 cached in LDS (one read), masked vals reused for pooling
__global__ __launch_bounds__(256) void k_fuse2(
    const float* __restrict__ x3, const int* __restrict__ gt,
    const float* __restrict__ dw, float* __restrict__ o_x2,
    float* __restrict__ act2, float* __restrict__ logits, int* __restrict__ idx2) {
  __shared__ float4 vals[196][8];      // 25088 B: x3 slice, then masked slice
  __shared__ float rv[32][8][4];       // 4096 B
  __shared__ int   ri[32][8][4];       // 4096 B
  __shared__ float red[10];
  int bid = blockIdx.x; int b = bid >> 4, cg = bid & 15;
  int t = threadIdx.x, c4 = t & 7, sp = t >> 3;
  int c0 = cg * 32 + c4 * 4, cq = c0 >> 2;
  const float4* ip = (const float4*)x3 + (size_t)b * 196 * 128;

  // phase A: argmax, cache x3 in LDS
  float bv[4] = {-1e30f, -1e30f, -1e30f, -1e30f};
  int bix[4] = {0, 0, 0, 0};
  for (int s = sp; s < 196; s += 32) {
    float4 v = ip[s * 128 + cq];
    vals[s][c4] = v;
    float vv[4] = {v.x, v.y, v.z, v.w};
#pragma unroll
    for (int k = 0; k < 4; ++k)
      if (vv[k] > bv[k]) { bv[k] = vv[k]; bix[k] = s; }
  }
#pragma unroll
  for (int k = 0; k < 4; ++k) { rv[sp][c4][k] = bv[k]; ri[sp][c4][k] = bix[k]; }
  __syncthreads();
  for (int st = 16; st >= 1; st >>= 1) {
    if (sp < st) {
#pragma unroll
      for (int k = 0; k < 4; ++k) {
        float v1 = rv[sp][c4][k], v2 = rv[sp + st][c4][k];
        int i1 = ri[sp][c4][k], i2 = ri[sp + st][c4][k];
        if (v2 > v1 || (v2 == v1 && i2 < i1)) { rv[sp][c4][k] = v2; ri[sp][c4][k] = i2; }
      }
    }
    __syncthreads();
  }
  int pi[4], pj[4];
#pragma unroll
  for (int k = 0; k < 4; ++k) {
    int id = ri[0][c4][k];
    pi[k] = id / 14; pj[k] = id - pi[k] * 14;
  }
  if (sp == 0)
    *(int4*)&idx2[b * 512 + c0] = make_int4(ri[0][c4][0], ri[0][c4][1], ri[0][c4][2], ri[0][c4][3]);
  if (t < 10) red[t] = 0.f;
  __syncthreads();   // before reusing rv

  // phase B: mask from LDS copy, write o_x2, overwrite vals with masked, sums
  float4* xo = (float4*)o_x2 + (size_t)b * 196 * 128;
  float sm[4] = {0.f, 0.f, 0.f, 0.f};
  for (int s = sp; s < 196; s += 32) {
    int i = s / 14, j = s - i * 14;
    float4 x = vals[s][c4];
    float xx[4] = {x.x, x.y, x.z, x.w};
    float mm[4];
#pragma unroll
    for (int k = 0; k < 4; ++k) {
      int di = i - pi[k]; di = di < 0 ? -di : di;
      int dj = j - pj[k]; dj = dj < 0 ? -dj : dj;
      float tp = TAO_F * fmaxf(1.0f - (float)(di + dj) * (1.0f / 7.0f), -1.0f);
      mm[k] = fmaxf(xx[k] * tp, 0.0f);
      sm[k] += mm[k];
    }
    float4 m4 = make_float4(mm[0], mm[1], mm[2], mm[3]);
    xo[s * 128 + cq] = m4;
    vals[s][c4] = m4;          // own cells only — no cross-thread hazard
  }
#pragma unroll
  for (int k = 0; k < 4; ++k) rv[sp][c4][k] = sm[k];
  __syncthreads();             // vals complete + rv ready
  for (int st = 16; st >= 1; st >>= 1) {
    if (sp < st) {
#pragma unroll
      for (int k = 0; k < 4; ++k) rv[sp][c4][k] += rv[sp + st][c4][k];
    }
    __syncthreads();
  }
  if (sp == 0) {
    int g = gt[b];
#pragma unroll
    for (int k = 0; k < 4; ++k)
      atomicAdd(&act2[(c0 + k) * 10 + g], rv[0][c4][k] * (1.0f / 196.0f));
  }

  // phase C: 2x2 max-pool from vals + dense partials
  float a[10] = {0.f,0.f,0.f,0.f,0.f,0.f,0.f,0.f,0.f,0.f};
  for (int pp = sp; pp < 49; pp += 32) {
    int ii = pp / 7, jj = pp - ii * 7;
    int s00 = (2 * ii) * 14 + 2 * jj;
    float4 v00 = vals[s00][c4], v01 = vals[s00 + 1][c4];
    float4 v10 = vals[s00 + 14][c4], v11 = vals[s00 + 15][c4];
    float pmx = fmaxf(fmaxf(v00.x, v01.x), fmaxf(v10.x, v11.x));
    float pmy = fmaxf(fmaxf(v00.y, v01.y), fmaxf(v10.y, v11.y));
    float pmz = fmaxf(fmaxf(v00.z, v01.z), fmaxf(v10.z, v11.z));
    float pmw = fmaxf(fmaxf(v00.w, v01.w), fmaxf(v10.w, v11.w));
    const float* wr = dw + ((size_t)((ii * 7 + jj) * 512 + c0)) * 10;
#pragma unroll
    for (int t2 = 0; t2 < 10; ++t2)
      a[t2] += pmx * wr[t2] + pmy * wr[10 + t2] + pmz * wr[20 + t2] + pmw * wr[30 + t2];
  }
  int lane = t & 63;
#pragma unroll
  for (int t2 = 0; t2 < 10; ++t2) {
    float v = a[t2];
    for (int off = 32; off > 0; off >>= 1) v += __shfl_down(v, off);
    if (lane == 0) atomicAdd(&red[t2], v);
  }
  __syncthreads();
  if (t < 10) atomicAdd(&logits[b * 10 + t], red[t]);
}

// ================= stats: cls bincount + fclass argmax per channel + softmax(probs)
__global__ void k_stats(const float* __restrict__ act1, const float* __restrict__ act2,
                        const float* __restrict__ as1, const float* __restrict__ as2,
                        const float* __restrict__ cs1, const float* __restrict__ cs2,
                        const int* __restrict__ gt, const float* __restrict__ logits,
                        const float* __restrict__ db, int* __restrict__ fc1,
                        int* __restrict__ fc2, float* __restrict__ o_probs) {
  __shared__ int scnt[10];
  int tid = threadIdx.x;              // 512
  if (tid < 10) scnt[tid] = 0;
  __syncthreads();
  if (tid < 128) atomicAdd(&scnt[gt[tid]], 1);
  __syncthreads();
  int c = tid;
  float best1 = -1e30f, best2 = -1e30f; int b1 = 0, b2 = 0;
#pragma unroll
  for (int g = 0; g < 10; ++g) {
    float cnt = (float)scnt[g];
    float cn1 = cs1[g] + cnt;
    float cn2 = cs2[g] + cnt;
    float a1 = act1[c * 10 + g] + as1[c * 10 + g];
    float a2 = act2[c * 10 + g] + as2[c * 10 + g];
    float f1 = (cn1 == 0.f) ? 0.f : a1 / cn1;
    float f2 = (cn2 == 0.f) ? 0.f : a2 / cn2;
    if (f1 > best1) { best1 = f1; b1 = g; }
    if (f2 > best2) { best2 = f2; b2 = g; }
  }
  fc1[c] = b1; fc2[c] = b2;
  if (tid < 128) {
    float l[10]; float m = -1e30f;
#pragma unroll
    for (int t2 = 0; t2 < 10; ++t2) { l[t2] = logits[tid * 10 + t2] + db[t2]; m = fmaxf(m, l[t2]); }
    float s = 0.f;
#pragma unroll
    for (int t2 = 0; t2 < 10; ++t2) { l[t2] = expf(l[t2] - m); s += l[t2]; }
    float inv = 1.0f / s;
#pragma unroll
    for (int t2 = 0; t2 < 10; ++t2) o_probs[tid * 10 + t2] = l[t2] * inv;
  }
}

// ================= losses: block=(b,row i), float4 over channels
__global__ __launch_bounds__(256) void k_loss(
    const int* __restrict__ idx1, const int* __restrict__ idx2,
    const int* __restrict__ fc1, const int* __restrict__ fc2,
    const int* __restrict__ gt, float* __restrict__ o1, float* __restrict__ o2) {
  int bid = blockIdx.x;                // 128*14
  int b = bid / 14, i = bid - b * 14;
  int t = threadIdx.x;
  int cgp = t & 127, jh = t >> 7;      // 128 float4 channel-groups, 2 j-halves
  int c0 = cgp * 4;
  int g = gt[b];
  int4 i1 = *(const int4*)&idx1[b * 512 + c0];
  int4 i2 = *(const int4*)&idx2[b * 512 + c0];
  int4 f1 = *(const int4*)&fc1[c0];
  int4 f2 = *(const int4*)&fc2[c0];
  float ms1[4] = {f1.x == g ? 1.f : 0.f, f1.y == g ? 1.f : 0.f,
                  f1.z == g ? 1.f : 0.f, f1.w == g ? 1.f : 0.f};
  float ms2[4] = {f2.x == g ? 1.f : 0.f, f2.y == g ? 1.f : 0.f,
                  f2.z == g ? 1.f : 0.f, f2.w == g ? 1.f : 0.f};
  int p1i[4], p1j[4], p2i[4], p2j[4];
  int ia1[4] = {i1.x, i1.y, i1.z, i1.w};
  int ia2[4] = {i2.x, i2.y, i2.z, i2.w};
#pragma unroll
  for (int k = 0; k < 4; ++k) {
    p1i[k] = ia1[k] / 14; p1j[k] = ia1[k] - p1i[k] * 14;
    p2i[k] = ia2[k] / 14; p2j[k] = ia2[k] - p2i[k] * 14;
  }
  float4* w1 = (float4*)o1 + ((size_t)b * 196 + i * 14) * 128 + (c0 >> 2);
  float4* w2 = (float4*)o2 + ((size_t)b * 196 + i * 14) * 128 + (c0 >> 2);
  for (int jj = 0; jj < 7; ++jj) {
    int j = jh * 7 + jj;
    float r1[4], r2[4];
#pragma unroll
    for (int k = 0; k < 4; ++k) {
      int d1i = i - p1i[k]; d1i = d1i < 0 ? -d1i : d1i;
      int d1j = j - p1j[k]; d1j = d1j < 0 ? -d1j : d1j;
      int d2i = i - p2i[k]; d2i = d2i < 0 ? -d2i : d2i;
      int d2j = j - p2j[k]; d2j = d2j < 0 ? -d2j : d2j;
      r1[k] = ms1[k] * (TAO_F * fmaxf(1.0f - (float)(d1i + d1j) * (1.0f / 7.0f), 0.0f));
      r2[k] = ms2[k] * (TAO_F * fmaxf(1.0f - (float)(d2i + d2j) * (1.0f / 7.0f), 0.0f));
    }
    w1[(size_t)j * 128] = make_float4(r1[0], r1[1], r1[2], r1[3]);
    w2[(size_t)j * 128] = make_float4(r2[0], r2[1], r2[2], r2[3]);
  }
}

extern "C" void kernel_launch(void* const* d_in, const int* in_sizes, int n_in,
                              void* d_out, int out_size, void* d_ws, size_t ws_size,
                              hipStream_t stream) {
  const float* inputs  = (const float*)d_in[0];
  const int*   gt      = (const int*)d_in[1];
  const float* conv_w  = (const float*)d_in[2];
  const float* conv_b  = (const float*)d_in[3];
  const float* dense_w = (const float*)d_in[4];
  const float* dense_b = (const float*)d_in[5];
  const float* as1     = (const float*)d_in[6];
  const float* as2     = (const float*)d_in[7];
  const float* cs1     = (const float*)d_in[8];
  const float* cs2     = (const float*)d_in[9];

  float* out = (float*)d_out;
  const size_t S = 12845056;              // 128*14*14*512
  float* o_probs = out;                   // 1280
  float* o_x1  = out + 1280;
  float* o_x2  = o_x1 + S;
  float* o_l1  = o_x2 + S;
  float* o_l2  = o_l1 + S;
  float* o_raw = o_l2 + S;
  float* o_t1  = o_raw + S;

  uint8_t* w8 = (uint8_t*)d_ws;
  __hip_bfloat16* x1p = (__hip_bfloat16*)w8;                 // 33,554,432 B
  float* x3  = (float*)(w8 + 33554432);                      // 51,380,224 B
  __hip_bfloat16* wT = (__hip_bfloat16*)(w8 + 84934656);     //  4,718,592 B
  int*   idx1 = (int*)(w8 + 89653248);                       //    262,144 B
  int*   idx2 = (int*)(w8 + 89915392);                       //    262,144 B
  float* act1 = (float*)(w8 + 90177536);                     //     20,480 B
  float* act2 = (float*)(w8 + 90198016);                     //     20,480 B
  float* logits = (float*)(w8 + 90218496);                   //      5,120 B
  int*   fc1  = (int*)(w8 + 90223616);                       //      2,048 B
  int*   fc2  = (int*)(w8 + 90225664);                       //      2,048 B

  hipMemsetAsync(x1p, 0, 33554432, stream);          // zero halo (interior overwritten)
  hipMemsetAsync(act1, 0, 46080, stream);            // act1+act2+logits contiguous

  k_pre   <<<576 + 2048, 256, 0, stream>>>(conv_w, wT, inputs, gt, o_raw, o_x1, o_t1,
                                           x1p, act1, idx1);
  k_gemm  <<<784, 256, 0, stream>>>(x1p, wT, conv_b, x3);
  k_fuse2 <<<2048, 256, 0, stream>>>(x3, gt, dense_w, o_x2, act2, logits, idx2);
  k_stats <<<1, 512, 0, stream>>>(act1, act2, as1, as2, cs1, cs2, gt, logits, dense_b,
                                  fc1, fc2, o_probs);
  k_loss  <<<1792, 256, 0, stream>>>(idx1, idx2, fc1, fc2, gt, o_l1, o_l2);
}

// Round 4
// 546.579 us; speedup vs baseline: 1.2282x; 1.0877x over previous
//
#include <hip/hip_runtime.h>
#include <hip/hip_bf16.h>
#include <stdint.h>

#define TAO_F (0.5f/196.0f)
#define A_SC 512.0f            // x1 pre-scale into e4m3 normal range
#define B_SC 64.0f             // w pre-scale
#define EPI (1.0f/32768.0f)    // undo A_SC*B_SC in epilogue

typedef float f32x4 __attribute__((ext_vector_type(4)));
typedef int   i32x4 __attribute__((ext_vector_type(4)));
typedef int   i32x8 __attribute__((ext_vector_type(8)));
typedef __attribute__((address_space(1))) const unsigned int u32_g;
typedef __attribute__((address_space(3))) unsigned int u32_l;

__device__ __forceinline__ void async_ld16(const void* g, void* l) {
  __builtin_amdgcn_global_load_lds((u32_g*)g, (u32_l*)l, 16, 0, 0);
}

// pack 4 floats -> 4 fp8 e4m3 bytes in one u32
__device__ __forceinline__ unsigned int pk_fp8x4(float a, float b, float c, float d) {
  int r = __builtin_amdgcn_cvt_pk_fp8_f32(a, b, 0, false);     // bytes 0,1
  r = __builtin_amdgcn_cvt_pk_fp8_f32(c, d, r, true);          // bytes 2,3
  return (unsigned int)r;
}

// ================= fused layer-1 body: argmax + raw copy + mask + fp8 pack + act1
// block = (b, cg): 32 channels; 256 thr = 8 float4-groups x 32 spatial partitions
__device__ __forceinline__ void fuse1_body(
    int bid, const float* __restrict__ in, const int* __restrict__ gt,
    float* __restrict__ o_raw, float* __restrict__ o_x1, float* __restrict__ o_t1,
    uint8_t* __restrict__ x1p8, float* __restrict__ act1,
    int* __restrict__ idx1, uint8_t* smem) {
  int b = bid >> 4, cg = bid & 15;
  int t = threadIdx.x;
  int c4 = t & 7, sp = t >> 3;
  int c0 = cg * 32 + c4 * 4;
  int cq = c0 >> 2;
  float (*rv)[8][4] = (float(*)[8][4])smem;            // 4096 B
  int   (*ri)[8][4] = (int(*)[8][4])(smem + 4096);     // 4096 B

  const float4* ip = (const float4*)in + (size_t)b * 196 * 128;
  float4* rp = (float4*)o_raw + (size_t)b * 196 * 128;

  // phase A: argmax (first-max) + raw copy, float4
  float bv[4] = {-1e30f, -1e30f, -1e30f, -1e30f};
  int bix[4] = {0, 0, 0, 0};
  for (int s = sp; s < 196; s += 32) {
    float4 v = ip[s * 128 + cq];
    rp[s * 128 + cq] = v;
    float vv[4] = {v.x, v.y, v.z, v.w};
#pragma unroll
    for (int k = 0; k < 4; ++k)
      if (vv[k] > bv[k]) { bv[k] = vv[k]; bix[k] = s; }
  }
#pragma unroll
  for (int k = 0; k < 4; ++k) { rv[sp][c4][k] = bv[k]; ri[sp][c4][k] = bix[k]; }
  __syncthreads();
  for (int st = 16; st >= 1; st >>= 1) {
    if (sp < st) {
#pragma unroll
      for (int k = 0; k < 4; ++k) {
        float v1 = rv[sp][c4][k], v2 = rv[sp + st][c4][k];
        int i1 = ri[sp][c4][k], i2 = ri[sp + st][c4][k];
        if (v2 > v1 || (v2 == v1 && i2 < i1)) { rv[sp][c4][k] = v2; ri[sp][c4][k] = i2; }
      }
    }
    __syncthreads();
  }
  int pi[4], pj[4];
#pragma unroll
  for (int k = 0; k < 4; ++k) {
    int id = ri[0][c4][k];
    pi[k] = id / 14; pj[k] = id - pi[k] * 14;
  }
  if (sp == 0)
    *(int4*)&idx1[b * 512 + c0] = make_int4(ri[0][c4][0], ri[0][c4][1], ri[0][c4][2], ri[0][c4][3]);
  __syncthreads();   // before reusing rv for sums

  // phase B: mask, write x1/t1/x1p8(fp8*A_SC), accumulate sums
  float4* xo = (float4*)o_x1 + (size_t)b * 196 * 128;
  float4* to = (float4*)o_t1 + (size_t)b * 196 * 128;
  float sm[4] = {0.f, 0.f, 0.f, 0.f};
  for (int s = sp; s < 196; s += 32) {
    int i = s / 14, j = s - i * 14;
    float4 x = ip[s * 128 + cq];
    float xx[4] = {x.x, x.y, x.z, x.w};
    float tp[4], mm[4];
#pragma unroll
    for (int k = 0; k < 4; ++k) {
      int di = i - pi[k]; di = di < 0 ? -di : di;
      int dj = j - pj[k]; dj = dj < 0 ? -dj : dj;
      tp[k] = TAO_F * fmaxf(1.0f - (float)(di + dj) * (1.0f / 7.0f), -1.0f);
      mm[k] = fmaxf(xx[k] * tp[k], 0.0f);
      sm[k] += mm[k];
    }
    xo[s * 128 + cq] = make_float4(mm[0], mm[1], mm[2], mm[3]);
    to[s * 128 + cq] = make_float4(tp[0], tp[1], tp[2], tp[3]);
    *(unsigned int*)&x1p8[((size_t)(b * 16 + i + 1) * 16 + (j + 1)) * 512 + c0] =
        pk_fp8x4(mm[0] * A_SC, mm[1] * A_SC, mm[2] * A_SC, mm[3] * A_SC);
  }
#pragma unroll
  for (int k = 0; k < 4; ++k) rv[sp][c4][k] = sm[k];
  __syncthreads();
  for (int st = 16; st >= 1; st >>= 1) {
    if (sp < st) {
#pragma unroll
      for (int k = 0; k < 4; ++k) rv[sp][c4][k] += rv[sp + st][c4][k];
    }
    __syncthreads();
  }
  if (sp == 0) {
    int g = gt[b];
#pragma unroll
    for (int k = 0; k < 4; ++k)
      atomicAdd(&act1[(c0 + k) * 10 + g], rv[0][c4][k] * (1.0f / 196.0f));
  }
}

// ================= k_pre: blocks <576 transpose conv_w -> wT fp8 (*B_SC); rest = fuse1
__global__ __launch_bounds__(256) void k_pre(
    const float* __restrict__ w, uint8_t* __restrict__ wT8,
    const float* __restrict__ in, const int* __restrict__ gt,
    float* __restrict__ o_raw, float* __restrict__ o_x1, float* __restrict__ o_t1,
    uint8_t* __restrict__ x1p8, float* __restrict__ act1, int* __restrict__ idx1) {
  __shared__ uint8_t smem[16640];
  if (blockIdx.x < 576) {
    float (*tile)[65] = (float(*)[65])smem;
    int bid = blockIdx.x;
    int r = bid / 64; int rem = bid - r * 64;
    int cib = (rem >> 3) * 64, cob = (rem & 7) * 64;
    int tid = threadIdx.x;
    int col = tid & 63, rw = tid >> 6;
#pragma unroll
    for (int p = 0; p < 16; ++p) {
      int row = p * 4 + rw;               // ci
      tile[row][col] = w[(size_t)(r * 512 + cib + row) * 512 + cob + col];
    }
    __syncthreads();
    // write phase: wT8[r][co][ci] fp8, 4 ci per thread
    int cw = tid & 15, rw2 = tid >> 4;    // ci group, co row within pass
#pragma unroll
    for (int p = 0; p < 4; ++p) {
      int co = p * 16 + rw2;
      unsigned int pk = pk_fp8x4(tile[cw * 4 + 0][co] * B_SC, tile[cw * 4 + 1][co] * B_SC,
                                 tile[cw * 4 + 2][co] * B_SC, tile[cw * 4 + 3][co] * B_SC);
      *(unsigned int*)&wT8[(size_t)(r * 512 + cob + co) * 512 + cib + cw * 4] = pk;
    }
  } else {
    fuse1_body(blockIdx.x - 576, in, gt, o_raw, o_x1, o_t1, x1p8, act1, idx1, smem);
  }
}

// ================= implicit-GEMM conv via MX-scaled fp8 MFMA (unit scales):
// x3 = relu((x1p8 (*) wT8) * EPI + bias), M=25088 N=512 K=4608, BK=128 fp8 bytes
__global__ __launch_bounds__(256, 3) void k_gemm(const uint8_t* __restrict__ x1p8,
                                                 const uint8_t* __restrict__ wT8,
                                                 const float* __restrict__ conv_b,
                                                 float* __restrict__ x3) {
  int bid = blockIdx.x;              // 196 Mtiles * 4 Ntiles
  int nt4 = bid & 3; int mt196 = bid >> 2;
  int m0 = mt196 * 128, co0 = nt4 * 128;
  int tid = threadIdx.x;
  int lane = tid & 63;

  __shared__ uint8_t As[128 * 128];  // [m][k] fp8, 16B slots XOR-swizzled by row&7
  __shared__ uint8_t Bs[128 * 128];  // [n][k]

  int srow = tid >> 3;               // 0..31 (row within pass)
  int sslot = tid & 7;               // 16B slot within 128B row
  int sx = (sslot ^ (srow & 7)) * 16;    // swizzled byte offset in global 128-run

  int baseA[4];
#pragma unroll
  for (int p = 0; p < 4; ++p) {
    int m = m0 + p * 32 + srow;
    int b = m / 196; int s = m - b * 196; int i = s / 14; int j = s - i * 14;
    baseA[p] = ((b * 16 + i + 1) * 16 + (j + 1)) * 512;
  }
  int baseB[4];
#pragma unroll
  for (int p = 0; p < 4; ++p) baseB[p] = (co0 + p * 32 + srow) * 512;

  f32x4 acc[4][4] = {};

  int m_off = (tid >> 7) * 64;        // wave/2
  int n_off = ((tid >> 6) & 1) * 64;  // wave%2
  int q = lane >> 4;
  int l16 = lane & 15;

  for (int r = 0; r < 9; ++r) {
    int offr = ((r / 3) * 16 + (r % 3) - 17) * 512;   // (di*16+dj)*512
    int wbase = r * 512 * 512;
    for (int cb = 0; cb < 4; ++cb) {
      int ko = cb * 128;
      __syncthreads();
#pragma unroll
      for (int p = 0; p < 4; ++p) {
        async_ld16(x1p8 + (baseA[p] + offr + ko + sx),
                   &As[(p * 32 + srow) * 128 + sslot * 16]);
        async_ld16(wT8 + (wbase + baseB[p] + ko + sx),
                   &Bs[(p * 32 + srow) * 128 + sslot * 16]);
      }
      __syncthreads();
      // fragments: lane holds k bytes [q*32, q*32+32) of its row = slots {2q,2q+1} pre-swizzle
      i32x8 af[4], bf[4];
#pragma unroll
      for (int tt = 0; tt < 4; ++tt) {
        int rowa = m_off + tt * 16 + l16;
        int e = rowa & 7;
        i32x4 lo = *(const i32x4*)&As[rowa * 128 + ((2 * q) ^ e) * 16];
        i32x4 hi = *(const i32x4*)&As[rowa * 128 + ((2 * q + 1) ^ e) * 16];
        af[tt] = (i32x8){lo.x, lo.y, lo.z, lo.w, hi.x, hi.y, hi.z, hi.w};
        int rowb = n_off + tt * 16 + l16;
        int eb = rowb & 7;
        i32x4 blo = *(const i32x4*)&Bs[rowb * 128 + ((2 * q) ^ eb) * 16];
        i32x4 bhi = *(const i32x4*)&Bs[rowb * 128 + ((2 * q + 1) ^ eb) * 16];
        bf[tt] = (i32x8){blo.x, blo.y, blo.z, blo.w, bhi.x, bhi.y, bhi.z, bhi.w};
      }
#pragma unroll
      for (int mt = 0; mt < 4; ++mt)
#pragma unroll
        for (int nt = 0; nt < 4; ++nt)
          acc[mt][nt] = __builtin_amdgcn_mfma_scale_f32_16x16x128_f8f6f4(
              af[mt], bf[nt], acc[mt][nt], 0, 0,           // cbsz=fp8, blgp=fp8
              0, 0x7F7F7F7F, 0, 0x7F7F7F7F);               // unit E8M0 scales (all bytes 127)
    }
  }
  // epilogue: undo pre-scales, bias + relu; C/D layout col=lane&15, row=(lane>>4)*4+reg
#pragma unroll
  for (int nt = 0; nt < 4; ++nt) {
    int col = co0 + n_off + nt * 16 + l16;
    float bias = conv_b[col];
#pragma unroll
    for (int mt = 0; mt < 4; ++mt) {
      int mrow = m0 + m_off + mt * 16 + q * 4;
#pragma unroll
      for (int rg = 0; rg < 4; ++rg) {
        float v = acc[mt][nt][rg] * EPI + bias;
        x3[(size_t)(mrow + rg) * 512 + col] = fmaxf(v, 0.0f);
      }
    }
  }
}

// ================= fused layer-2: argmax + mask + act2 + pool + dense partials
__global__ __launch_bounds__(256) void k_fuse2(
    const float* __restrict__ x3, const int* __restrict__ gt,
    const float* __restrict__ dw, float* __restrict__ o_x2,
    float* __restrict__ act2, float* __restrict__ logits, int* __restrict__ idx2) {
  __shared__ float4 vals[196][8];      // 25088 B: x3 slice, then masked slice
  __shared__ float rv[32][8][4];       // 4096 B
  __shared__ int   ri[32][8][4];       // 4096 B
  __shared__ float red[10];
  int bid = blockIdx.x; int b = bid >> 4, cg = bid & 15;
  int t = threadIdx.x, c4 = t & 7, sp = t >> 3;
  int c0 = cg * 32 + c4 * 4, cq = c0 >> 2;
  const float4* ip = (const float4*)x3 + (size_t)b * 196 * 128;

  float bv[4] = {-1e30f, -1e30f, -1e30f, -1e30f};
  int bix[4] = {0, 0, 0, 0};
  for (int s = sp; s < 196; s += 32) {
    float4 v = ip[s * 128 + cq];
    vals[s][c4] = v;
    float vv[4] = {v.x, v.y, v.z, v.w};
#pragma unroll
    for (int k = 0; k < 4; ++k)
      if (vv[k] > bv[k]) { bv[k] = vv[k]; bix[k] = s; }
  }
#pragma unroll
  for (int k = 0; k < 4; ++k) { rv[sp][c4][k] = bv[k]; ri[sp][c4][k] = bix[k]; }
  __syncthreads();
  for (int st = 16; st >= 1; st >>= 1) {
    if (sp < st) {
#pragma unroll
      for (int k = 0; k < 4; ++k) {
        float v1 = rv[sp][c4][k], v2 = rv[sp + st][c4][k];
        int i1 = ri[sp][c4][k], i2 = ri[sp + st][c4][k];
        if (v2 > v1 || (v2 == v1 && i2 < i1)) { rv[sp][c4][k] = v2; ri[sp][c4][k] = i2; }
      }
    }
    __syncthreads();
  }
  int pi[4], pj[4];
#pragma unroll
  for (int k = 0; k < 4; ++k) {
    int id = ri[0][c4][k];
    pi[k] = id / 14; pj[k] = id - pi[k] * 14;
  }
  if (sp == 0)
    *(int4*)&idx2[b * 512 + c0] = make_int4(ri[0][c4][0], ri[0][c4][1], ri[0][c4][2], ri[0][c4][3]);
  if (t < 10) red[t] = 0.f;
  __syncthreads();

  float4* xo = (float4*)o_x2 + (size_t)b * 196 * 128;
  float sm[4] = {0.f, 0.f, 0.f, 0.f};
  for (int s = sp; s < 196; s += 32) {
    int i = s / 14, j = s - i * 14;
    float4 x = vals[s][c4];
    float xx[4] = {x.x, x.y, x.z, x.w};
    float mm[4];
#pragma unroll
    for (int k = 0; k < 4; ++k) {
      int di = i - pi[k]; di = di < 0 ? -di : di;
      int dj = j - pj[k]; dj = dj < 0 ? -dj : dj;
      float tp = TAO_F * fmaxf(1.0f - (float)(di + dj) * (1.0f / 7.0f), -1.0f);
      mm[k] = fmaxf(xx[k] * tp, 0.0f);
      sm[k] += mm[k];
    }
    float4 m4 = make_float4(mm[0], mm[1], mm[2], mm[3]);
    xo[s * 128 + cq] = m4;
    vals[s][c4] = m4;
  }
#pragma unroll
  for (int k = 0; k < 4; ++k) rv[sp][c4][k] = sm[k];
  __syncthreads();
  for (int st = 16; st >= 1; st >>= 1) {
    if (sp < st) {
#pragma unroll
      for (int k = 0; k < 4; ++k) rv[sp][c4][k] += rv[sp + st][c4][k];
    }
    __syncthreads();
  }
  if (sp == 0) {
    int g = gt[b];
#pragma unroll
    for (int k = 0; k < 4; ++k)
      atomicAdd(&act2[(c0 + k) * 10 + g], rv[0][c4][k] * (1.0f / 196.0f));
  }

  float a[10] = {0.f,0.f,0.f,0.f,0.f,0.f,0.f,0.f,0.f,0.f};
  for (int pp = sp; pp < 49; pp += 32) {
    int ii = pp / 7, jj = pp - ii * 7;
    int s00 = (2 * ii) * 14 + 2 * jj;
    float4 v00 = vals[s00][c4], v01 = vals[s00 + 1][c4];
    float4 v10 = vals[s00 + 14][c4], v11 = vals[s00 + 15][c4];
    float pmx = fmaxf(fmaxf(v00.x, v01.x), fmaxf(v10.x, v11.x));
    float pmy = fmaxf(fmaxf(v00.y, v01.y), fmaxf(v10.y, v11.y));
    float pmz = fmaxf(fmaxf(v00.z, v01.z), fmaxf(v10.z, v11.z));
    float pmw = fmaxf(fmaxf(v00.w, v01.w), fmaxf(v10.w, v11.w));
    const float* wr = dw + ((size_t)((ii * 7 + jj) * 512 + c0)) * 10;
#pragma unroll
    for (int t2 = 0; t2 < 10; ++t2)
      a[t2] += pmx * wr[t2] + pmy * wr[10 + t2] + pmz * wr[20 + t2] + pmw * wr[30 + t2];
  }
  int lane = t & 63;
#pragma unroll
  for (int t2 = 0; t2 < 10; ++t2) {
    float v = a[t2];
    for (int off = 32; off > 0; off >>= 1) v += __shfl_down(v, off);
    if (lane == 0) atomicAdd(&red[t2], v);
  }
  __syncthreads();
  if (t < 10) atomicAdd(&logits[b * 10 + t], red[t]);
}

// ================= stats: cls bincount + fclass argmax per channel + softmax(probs)
__global__ void k_stats(const float* __restrict__ act1, const float* __restrict__ act2,
                        const float* __restrict__ as1, const float* __restrict__ as2,
                        const float* __restrict__ cs1, const float* __restrict__ cs2,
                        const int* __restrict__ gt, const float* __restrict__ logits,
                        const float* __restrict__ db, int* __restrict__ fc1,
                        int* __restrict__ fc2, float* __restrict__ o_probs) {
  __shared__ int scnt[10];
  int tid = threadIdx.x;              // 512
  if (tid < 10) scnt[tid] = 0;
  __syncthreads();
  if (tid < 128) atomicAdd(&scnt[gt[tid]], 1);
  __syncthreads();
  int c = tid;
  float best1 = -1e30f, best2 = -1e30f; int b1 = 0, b2 = 0;
#pragma unroll
  for (int g = 0; g < 10; ++g) {
    float cnt = (float)scnt[g];
    float cn1 = cs1[g] + cnt;
    float cn2 = cs2[g] + cnt;
    float a1 = act1[c * 10 + g] + as1[c * 10 + g];
    float a2 = act2[c * 10 + g] + as2[c * 10 + g];
    float f1 = (cn1 == 0.f) ? 0.f : a1 / cn1;
    float f2 = (cn2 == 0.f) ? 0.f : a2 / cn2;
    if (f1 > best1) { best1 = f1; b1 = g; }
    if (f2 > best2) { best2 = f2; b2 = g; }
  }
  fc1[c] = b1; fc2[c] = b2;
  if (tid < 128) {
    float l[10]; float m = -1e30f;
#pragma unroll
    for (int t2 = 0; t2 < 10; ++t2) { l[t2] = logits[tid * 10 + t2] + db[t2]; m = fmaxf(m, l[t2]); }
    float s = 0.f;
#pragma unroll
    for (int t2 = 0; t2 < 10; ++t2) { l[t2] = expf(l[t2] - m); s += l[t2]; }
    float inv = 1.0f / s;
#pragma unroll
    for (int t2 = 0; t2 < 10; ++t2) o_probs[tid * 10 + t2] = l[t2] * inv;
  }
}

// ================= losses: block=(b,row i), float4 over channels
__global__ __launch_bounds__(256) void k_loss(
    const int* __restrict__ idx1, const int* __restrict__ idx2,
    const int* __restrict__ fc1, const int* __restrict__ fc2,
    const int* __restrict__ gt, float* __restrict__ o1, float* __restrict__ o2) {
  int bid = blockIdx.x;                // 128*14
  int b = bid / 14, i = bid - b * 14;
  int t = threadIdx.x;
  int cgp = t & 127, jh = t >> 7;      // 128 float4 channel-groups, 2 j-halves
  int c0 = cgp * 4;
  int g = gt[b];
  int4 i1 = *(const int4*)&idx1[b * 512 + c0];
  int4 i2 = *(const int4*)&idx2[b * 512 + c0];
  int4 f1 = *(const int4*)&fc1[c0];
  int4 f2 = *(const int4*)&fc2[c0];
  float ms1[4] = {f1.x == g ? 1.f : 0.f, f1.y == g ? 1.f : 0.f,
                  f1.z == g ? 1.f : 0.f, f1.w == g ? 1.f : 0.f};
  float ms2[4] = {f2.x == g ? 1.f : 0.f, f2.y == g ? 1.f : 0.f,
                  f2.z == g ? 1.f : 0.f, f2.w == g ? 1.f : 0.f};
  int p1i[4], p1j[4], p2i[4], p2j[4];
  int ia1[4] = {i1.x, i1.y, i1.z, i1.w};
  int ia2[4] = {i2.x, i2.y, i2.z, i2.w};
#pragma unroll
  for (int k = 0; k < 4; ++k) {
    p1i[k] = ia1[k] / 14; p1j[k] = ia1[k] - p1i[k] * 14;
    p2i[k] = ia2[k] / 14; p2j[k] = ia2[k] - p2i[k] * 14;
  }
  float4* w1 = (float4*)o1 + ((size_t)b * 196 + i * 14) * 128 + (c0 >> 2);
  float4* w2 = (float4*)o2 + ((size_t)b * 196 + i * 14) * 128 + (c0 >> 2);
  for (int jj = 0; jj < 7; ++jj) {
    int j = jh * 7 + jj;
    float r1[4], r2[4];
#pragma unroll
    for (int k = 0; k < 4; ++k) {
      int d1i = i - p1i[k]; d1i = d1i < 0 ? -d1i : d1i;
      int d1j = j - p1j[k]; d1j = d1j < 0 ? -d1j : d1j;
      int d2i = i - p2i[k]; d2i = d2i < 0 ? -d2i : d2i;
      int d2j = j - p2j[k]; d2j = d2j < 0 ? -d2j : d2j;
      r1[k] = ms1[k] * (TAO_F * fmaxf(1.0f - (float)(d1i + d1j) * (1.0f / 7.0f), 0.0f));
      r2[k] = ms2[k] * (TAO_F * fmaxf(1.0f - (float)(d2i + d2j) * (1.0f / 7.0f), 0.0f));
    }
    w1[(size_t)j * 128] = make_float4(r1[0], r1[1], r1[2], r1[3]);
    w2[(size_t)j * 128] = make_float4(r2[0], r2[1], r2[2], r2[3]);
  }
}

extern "C" void kernel_launch(void* const* d_in, const int* in_sizes, int n_in,
                              void* d_out, int out_size, void* d_ws, size_t ws_size,
                              hipStream_t stream) {
  const float* inputs  = (const float*)d_in[0];
  const int*   gt      = (const int*)d_in[1];
  const float* conv_w  = (const float*)d_in[2];
  const float* conv_b  = (const float*)d_in[3];
  const float* dense_w = (const float*)d_in[4];
  const float* dense_b = (const float*)d_in[5];
  const float* as1     = (const float*)d_in[6];
  const float* as2     = (const float*)d_in[7];
  const float* cs1     = (const float*)d_in[8];
  const float* cs2     = (const float*)d_in[9];

  float* out = (float*)d_out;
  const size_t S = 12845056;              // 128*14*14*512
  float* o_probs = out;                   // 1280
  float* o_x1  = out + 1280;
  float* o_x2  = o_x1 + S;
  float* o_l1  = o_x2 + S;
  float* o_l2  = o_l1 + S;
  float* o_raw = o_l2 + S;
  float* o_t1  = o_raw + S;

  uint8_t* w8 = (uint8_t*)d_ws;
  uint8_t* x1p8 = w8;                                        // 16,777,216 B (fp8, halo)
  float*   x3   = (float*)(w8 + 16777216);                   // 51,380,224 B
  uint8_t* wT8  = w8 + 68157440;                             //  2,359,296 B
  int*   idx1 = (int*)(w8 + 70516736);                       //    262,144 B
  int*   idx2 = (int*)(w8 + 70778880);                       //    262,144 B
  float* act1 = (float*)(w8 + 71041024);                     //     20,480 B
  float* act2 = (float*)(w8 + 71061504);                     //     20,480 B
  float* logits = (float*)(w8 + 71081984);                   //      5,120 B
  int*   fc1  = (int*)(w8 + 71087104);                       //      2,048 B
  int*   fc2  = (int*)(w8 + 71089152);                       //      2,048 B

  hipMemsetAsync(x1p8, 0, 16777216, stream);         // zero halo (fp8 zero = 0x00)
  hipMemsetAsync(act1, 0, 46080, stream);            // act1+act2+logits contiguous

  k_pre   <<<576 + 2048, 256, 0, stream>>>(conv_w, wT8, inputs, gt, o_raw, o_x1, o_t1,
                                           x1p8, act1, idx1);
  k_gemm  <<<784, 256, 0, stream>>>(x1p8, wT8, conv_b, x3);
  k_fuse2 <<<2048, 256, 0, stream>>>(x3, gt, dense_w, o_x2, act2, logits, idx2);
  k_stats <<<1, 512, 0, stream>>>(act1, act2, as1, as2, cs1, cs2, gt, logits, dense_b,
                                  fc1, fc2, o_probs);
  k_loss  <<<1792, 256, 0, stream>>>(idx1, idx2, fc1, fc2, gt, o_l1, o_l2);
}